// Round 7
// baseline (211.835 us; speedup 1.0000x reference)
//
#include <hip/hip_runtime.h>

typedef float f32x4 __attribute__((ext_vector_type(4)));
typedef short s16x8 __attribute__((ext_vector_type(8)));
typedef unsigned int u32;
typedef unsigned long long u64;
typedef unsigned short ush;

#define CD    256
#define NB    64
#define NBETA 512
#define NHID  512
#define PPB   32    // positions per fused block

__device__ __forceinline__ ush f2bf(float x) {
    u32 u = __builtin_bit_cast(u32, x);
    u += 0x7fffu + ((u >> 16) & 1u);
    return (ush)(u >> 16);
}
__device__ __forceinline__ float bf2f(ush h) {
    u32 u = ((u32)h) << 16;
    return __builtin_bit_cast(float, u);
}

// ---------------------------------------------------------------------------
// Prep: hws[b][beta] = h_t[b]·W_h_w[beta] + W_h_b[beta] + W_b[beta] (bf16);
//       wwb = bf16(W_w) [512][256].
// ---------------------------------------------------------------------------
__global__ __launch_bounds__(512) void prep_kernel(
    const float* __restrict__ h_t, const float* __restrict__ W_h_w,
    const float* __restrict__ W_h_b, const float* __restrict__ W_w,
    const float* __restrict__ W_b,
    ush* __restrict__ hws, ush* __restrict__ wwb)
{
    const int blk = blockIdx.x;
    const int tid = threadIdx.x;
    if (blk < NB) {
        __shared__ float hrow[NHID];
        hrow[tid] = h_t[blk * NHID + tid];
        __syncthreads();
        const float* wr = W_h_w + tid * NHID;
        float a0 = 0.f, a1 = 0.f, a2 = 0.f, a3 = 0.f;
        #pragma unroll 4
        for (int h = 0; h < NHID; h += 4) {
            f32x4 wv = *(const f32x4*)(wr + h);
            a0 = fmaf(wv.x, hrow[h], a0);
            a1 = fmaf(wv.y, hrow[h + 1], a1);
            a2 = fmaf(wv.z, hrow[h + 2], a2);
            a3 = fmaf(wv.w, hrow[h + 3], a3);
        }
        float acc = (a0 + a1) + (a2 + a3) + W_h_b[tid] + W_b[tid];
        hws[blk * NBETA + tid] = f2bf(acc);   // [b][beta]
    } else {
        const int idx = ((blk - NB) * 512 + tid) * 8;
        f32x4 a = *(const f32x4*)(W_w + idx);
        f32x4 b = *(const f32x4*)(W_w + idx + 4);
        s16x8 pk;
        pk[0] = (short)f2bf(a.x); pk[1] = (short)f2bf(a.y);
        pk[2] = (short)f2bf(a.z); pk[3] = (short)f2bf(a.w);
        pk[4] = (short)f2bf(b.x); pk[5] = (short)f2bf(b.y);
        pk[6] = (short)f2bf(b.z); pk[7] = (short)f2bf(b.w);
        *(s16x8*)(wwb + idx) = pk;
    }
}

// ---------------------------------------------------------------------------
// Fused: block = 1024 thr (16 waves x 32 betas = ALL 512 betas), handles
// (b-half of 32) x (32 positions). V staged to LDS ONCE, used for both the
// MFMA (E computation) and the weighted sum -> V read from HBM exactly once.
// W_w A-fragments permanent in regs (64 VGPR); hterm permanent (8 VGPR).
// 1 block/CU, (1024,4) => 128-reg budget (round-4/5 lesson: acc set must
// fit the budget; here peak ~120).
// ---------------------------------------------------------------------------
__global__ __launch_bounds__(1024, 4) void fused(
    const float* __restrict__ V,
    const ush* __restrict__ wwb,
    const ush* __restrict__ hws,
    const float* __restrict__ beta_w,
    const float* __restrict__ beta_b,
    float* __restrict__ num,
    float* __restrict__ lsum)
{
    __shared__ __align__(16) char VtB[2][16384];  // [32 b][256 c] bf16 swizzled
    __shared__ float bwS[NBETA];
    __shared__ float ew[16][32];

    const int tid = threadIdx.x;
    const int l = tid & 63, w = tid >> 6, g = l >> 4, r = l & 15;
    const int bl = tid & 31, cs = tid >> 5;       // b-lane, c-slice of 8
    const int bh = blockIdx.x & 1, chunk = blockIdx.x >> 1;

    if (tid < NBETA) bwS[tid] = beta_w[tid];
    const float bbias = beta_b[0];

    // permanent A fragments: beta = w*32 + m*16 + r  (full 512 across waves)
    const ush* wbase = wwb + (size_t)(w * 32 + r) * CD + g * 8;
    s16x8 a[2][8];
    #pragma unroll
    for (int m = 0; m < 2; ++m)
        #pragma unroll
        for (int ks = 0; ks < 8; ++ks)
            a[m][ks] = *(const s16x8*)(wbase + m * (16 * CD) + ks * 32);

    // permanent hterm: ua[m][n] = betas (w*32+m*16+g*4..+4) at b = bh*32+n*16+r
    const ush* hbase = hws + (size_t)(bh * 32 + r) * NBETA + w * 32 + g * 4;
    u64 ua[2][2];
    #pragma unroll
    for (int m = 0; m < 2; ++m)
        #pragma unroll
        for (int n = 0; n < 2; ++n)
            ua[m][n] = *(const u64*)(hbase + n * (16 * NBETA) + m * 16);

    const int p0 = chunk * PPB;
    const float* vbase = V + (size_t)p0 * (CD * NB) + bh * 32 + bl;
    const int vswz = (bl & 7) << 4;
    const int xr4 = (r & 7) << 4;

    float cacc[8];
    #pragma unroll
    for (int j = 0; j < 8; ++j) cacc[j] = 0.f;
    float lacc = 0.f;

    // prologue: stage position 0 (each thread: 8 c-values at its b)
    {
        float nv[8];
        #pragma unroll
        for (int j = 0; j < 8; ++j)
            nv[j] = vbase[(cs * 8 + j) * NB];
        s16x8 pk;
        #pragma unroll
        for (int j = 0; j < 8; ++j) pk[j] = (short)f2bf(nv[j]);
        *(s16x8*)(VtB[0] + bl * 512 + ((cs * 16) ^ vswz)) = pk;
    }
    __syncthreads();

    for (int i = 0; i < PPB; ++i) {
        const char* vt = VtB[i & 1];
        const bool pf = (i + 1 < PPB);

        // issue next-position loads; land under K-loop + epilogue
        float nv[8];
        if (pf) {
            const float* vp = vbase + (size_t)(i + 1) * (CD * NB);
            #pragma unroll
            for (int j = 0; j < 8; ++j)
                nv[j] = vp[(cs * 8 + j) * NB];
        }

        // acc init = hterm (position-invariant registers)
        f32x4 acc[2][2];
        #pragma unroll
        for (int m = 0; m < 2; ++m)
            #pragma unroll
            for (int n = 0; n < 2; ++n) {
                u64 h = ua[m][n];
                acc[m][n] = (f32x4){bf2f((ush)h), bf2f((ush)(h >> 16)),
                                    bf2f((ush)(h >> 32)), bf2f((ush)(h >> 48))};
            }

        // K-loop: pure LDS + MFMA (A in regs)
        const char* vrow = vt + r * 512;
        #pragma unroll
        for (int ks = 0; ks < 8; ++ks) {
            const int off = ((ks << 6) | (g << 4)) ^ xr4;
            s16x8 b0 = *(const s16x8*)(vrow + off);
            s16x8 b1 = *(const s16x8*)(vrow + 8192 + off);
            #pragma unroll
            for (int m = 0; m < 2; ++m) {
                acc[m][0] = __builtin_amdgcn_mfma_f32_16x16x32_bf16(a[m][ks], b0, acc[m][0], 0, 0, 0);
                acc[m][1] = __builtin_amdgcn_mfma_f32_16x16x32_bf16(a[m][ks], b1, acc[m][1], 0, 0, 0);
            }
        }

        // epilogue: pe_n = sum_{m,q} tanh(acc)*bw over this wave's 32 betas
        float pe0 = 0.f, pe1 = 0.f;
        #pragma unroll
        for (int m = 0; m < 2; ++m) {
            f32x4 bwv = *(const f32x4*)(&bwS[w * 32 + m * 16 + g * 4]);
            #pragma unroll
            for (int q = 0; q < 4; ++q) {
                float x0 = acc[m][0][q], x1 = acc[m][1][q];
                float t0 = 1.f - 2.f * __builtin_amdgcn_rcpf(1.f + __expf(x0 + x0));
                float t1 = 1.f - 2.f * __builtin_amdgcn_rcpf(1.f + __expf(x1 + x1));
                pe0 = fmaf(t0, bwv[q], pe0);
                pe1 = fmaf(t1, bwv[q], pe1);
            }
        }
        pe0 += __shfl_xor(pe0, 16, 64); pe0 += __shfl_xor(pe0, 32, 64);
        pe1 += __shfl_xor(pe1, 16, 64); pe1 += __shfl_xor(pe1, 32, 64);
        if (l < 16) { ew[w][l] = pe0; ew[w][16 + l] = pe1; }

        // stage next position into the other buffer
        if (pf) {
            s16x8 pk;
            #pragma unroll
            for (int j = 0; j < 8; ++j) pk[j] = (short)f2bf(nv[j]);
            *(s16x8*)(VtB[(i + 1) & 1] + bl * 512 + ((cs * 16) ^ vswz)) = pk;
        }
        __syncthreads();   // ew + next-buffer staging complete

        // weight + accumulate from the SAME staged tile (no 2nd HBM pass)
        float e = bbias;
        #pragma unroll
        for (int wv = 0; wv < 16; ++wv) e += ew[wv][bl];
        float wgt = __expf(e);
        lacc += wgt;
        s16x8 v = *(const s16x8*)(vt + bl * 512 + ((cs * 16) ^ vswz));
        #pragma unroll
        for (int j = 0; j < 8; ++j)
            cacc[j] = fmaf(wgt, bf2f((ush)v[j]), cacc[j]);
        __syncthreads();   // vt reads done before iter i+1 re-stages it
    }

    // partials: num[block][32 b][256 c]
    float* np = num + (size_t)blockIdx.x * (32 * CD) + bl * CD + cs * 8;
    *(f32x4*)(np)     = (f32x4){cacc[0], cacc[1], cacc[2], cacc[3]};
    *(f32x4*)(np + 4) = (f32x4){cacc[4], cacc[5], cacc[6], cacc[7]};
    if (cs == 0) lsum[blockIdx.x * 32 + bl] = lacc;
}

// ---------------------------------------------------------------------------
// Combine: out[b][c] = sum_ch num[ch*2+bh][bl][c] / sum_ch lsum[ch*2+bh][bl]
// grid = 64 (b), 256 threads (c).
// ---------------------------------------------------------------------------
__global__ __launch_bounds__(256) void combine3(
    const float* __restrict__ num, const float* __restrict__ lsum,
    float* __restrict__ out)
{
    const int b = blockIdx.x, c = threadIdx.x;
    const int bh = b >> 5, bl = b & 31;
    float s0 = 0.f, s1 = 0.f, ls = 0.f;
    #pragma unroll 4
    for (int ch = 0; ch < 128; ch += 2) {
        const int w0 = ch * 2 + bh, w1 = (ch + 1) * 2 + bh;
        s0 += num[(size_t)w0 * (32 * CD) + bl * CD + c];
        s1 += num[(size_t)w1 * (32 * CD) + bl * CD + c];
        ls += lsum[w0 * 32 + bl] + lsum[w1 * 32 + bl];
    }
    out[b * CD + c] = (s0 + s1) / ls;
}

extern "C" void kernel_launch(void* const* d_in, const int* in_sizes, int n_in,
                              void* d_out, int out_size, void* d_ws, size_t ws_size,
                              hipStream_t stream)
{
    (void)in_sizes; (void)n_in; (void)out_size; (void)ws_size;
    const float* V      = (const float*)d_in[0];
    const float* h_t    = (const float*)d_in[1];
    const float* W_h_w  = (const float*)d_in[2];
    const float* W_h_b  = (const float*)d_in[3];
    const float* W_w    = (const float*)d_in[4];
    const float* W_b    = (const float*)d_in[5];
    const float* beta_w = (const float*)d_in[6];
    const float* beta_b = (const float*)d_in[7];

    char* ws = (char*)d_ws;
    ush*   wwb = (ush*)ws;                                   // 256 KB
    ush*   hws = (ush*)(ws + 262144);                        // 64 KB
    float* num = (float*)(ws + 262144 + 65536);              // 8.4 MB
    float* lsm = (float*)(ws + 262144 + 65536 + 8388608);    // 32 KB

    hipLaunchKernelGGL(prep_kernel, dim3(96), dim3(512), 0, stream,
                       h_t, W_h_w, W_h_b, W_w, W_b, hws, wwb);
    hipLaunchKernelGGL(fused, dim3(256), dim3(1024), 0, stream,
                       V, wwb, hws, beta_w, beta_b, num, lsm);
    hipLaunchKernelGGL(combine3, dim3(64), dim3(256), 0, stream,
                       num, lsm, (float*)d_out);
}

// Round 8
// 186.142 us; speedup vs baseline: 1.1380x; 1.1380x over previous
//
#include <hip/hip_runtime.h>

typedef float f32x4 __attribute__((ext_vector_type(4)));
typedef short s16x8 __attribute__((ext_vector_type(8)));
typedef unsigned int u32;
typedef u32 u32x4 __attribute__((ext_vector_type(4)));
typedef unsigned long long u64;
typedef unsigned short ush;

#define CD    256
#define NB    64
#define NBETA 512
#define NHID  512
#define PPB   32    // positions per fused block

__device__ __forceinline__ ush f2bf(float x) {
    u32 u = __builtin_bit_cast(u32, x);
    u += 0x7fffu + ((u >> 16) & 1u);
    return (ush)(u >> 16);
}
__device__ __forceinline__ float bf2f(ush h) {
    u32 u = ((u32)h) << 16;
    return __builtin_bit_cast(float, u);
}
__device__ __forceinline__ u32 cvtpk(float lo, float hi) {
    u32 r;
    asm("v_cvt_pk_bf16_f32 %0, %1, %2" : "=v"(r) : "v"(lo), "v"(hi));
    return r;
}
__device__ __forceinline__ float fexp2(float x) {  // 2^x
    float r;
    asm("v_exp_f32 %0, %1" : "=v"(r) : "v"(x));
    return r;
}

// ---------------------------------------------------------------------------
// Prep: hws[b][beta] = h_t[b]·W_h_w[beta] + W_h_b[beta] + W_b[beta] (bf16);
//       wwb = bf16(W_w) [512][256].
// ---------------------------------------------------------------------------
__global__ __launch_bounds__(512) void prep_kernel(
    const float* __restrict__ h_t, const float* __restrict__ W_h_w,
    const float* __restrict__ W_h_b, const float* __restrict__ W_w,
    const float* __restrict__ W_b,
    ush* __restrict__ hws, ush* __restrict__ wwb)
{
    const int blk = blockIdx.x;
    const int tid = threadIdx.x;
    if (blk < NB) {
        __shared__ float hrow[NHID];
        hrow[tid] = h_t[blk * NHID + tid];
        __syncthreads();
        const float* wr = W_h_w + tid * NHID;
        float a0 = 0.f, a1 = 0.f, a2 = 0.f, a3 = 0.f;
        #pragma unroll 4
        for (int h = 0; h < NHID; h += 4) {
            f32x4 wv = *(const f32x4*)(wr + h);
            a0 = fmaf(wv.x, hrow[h], a0);
            a1 = fmaf(wv.y, hrow[h + 1], a1);
            a2 = fmaf(wv.z, hrow[h + 2], a2);
            a3 = fmaf(wv.w, hrow[h + 3], a3);
        }
        float acc = (a0 + a1) + (a2 + a3) + W_h_b[tid] + W_b[tid];
        hws[blk * NBETA + tid] = f2bf(acc);   // [b][beta]
    } else {
        const int idx = ((blk - NB) * 512 + tid) * 8;
        f32x4 a = *(const f32x4*)(W_w + idx);
        f32x4 b = *(const f32x4*)(W_w + idx + 4);
        s16x8 pk;
        pk[0] = (short)f2bf(a.x); pk[1] = (short)f2bf(a.y);
        pk[2] = (short)f2bf(a.z); pk[3] = (short)f2bf(a.w);
        pk[4] = (short)f2bf(b.x); pk[5] = (short)f2bf(b.y);
        pk[6] = (short)f2bf(b.z); pk[7] = (short)f2bf(b.w);
        *(s16x8*)(wwb + idx) = pk;
    }
}

// ---------------------------------------------------------------------------
// Fused: 1024 thr (16 waves x 32 betas = all 512), block = (b-half, 32 pos).
// V read from HBM exactly once. Round-8 schedule:
//   - 3-buffer Vt rotation, ONE barrier per position
//   - prefetch distance 2: stage from loads issued LAST iteration
//   - full-range (bl&15) XOR swizzle: conflict-free b128 on all LDS paths
//   - epilogue: pe = base + sum nb*sigmoid(2x), nb=-2bw (LDS), base=sum bw
// ---------------------------------------------------------------------------
__global__ __launch_bounds__(1024, 4) void fused(
    const float* __restrict__ V,
    const ush* __restrict__ wwb,
    const ush* __restrict__ hws,
    const float* __restrict__ beta_w,
    const float* __restrict__ beta_b,
    float* __restrict__ num,
    float* __restrict__ lsum)
{
    __shared__ __align__(16) char VtB[3][16384];  // [32 b][256 c] bf16 swz
    __shared__ float nbS[NBETA];                  // -2*beta_w
    __shared__ float ew[2][16][32];               // [parity][wave][b]

    const int tid = threadIdx.x;
    const int l = tid & 63, w = tid >> 6, g = l >> 4, r = l & 15;
    const int bl = tid & 31, cs = tid >> 5;       // b-lane, c-slice of 8
    const int bh = blockIdx.x & 1, chunk = blockIdx.x >> 1;

    if (tid < NBETA) nbS[tid] = -2.f * beta_w[tid];
    const float bbias = beta_b[0];

    // per-lane base = sum of this lane's 8 bw values (position-invariant)
    f32x4 bw0 = *(const f32x4*)(beta_w + w * 32 + g * 4);
    f32x4 bw1 = *(const f32x4*)(beta_w + w * 32 + 16 + g * 4);
    const float base = (bw0.x + bw0.y) + (bw0.z + bw0.w)
                     + (bw1.x + bw1.y) + (bw1.z + bw1.w);

    // permanent A fragments: beta = w*32 + m*16 + r
    const ush* wbase = wwb + (size_t)(w * 32 + r) * CD + g * 8;
    s16x8 a[2][8];
    #pragma unroll
    for (int m = 0; m < 2; ++m)
        #pragma unroll
        for (int ks = 0; ks < 8; ++ks)
            a[m][ks] = *(const s16x8*)(wbase + m * (16 * CD) + ks * 32);

    // permanent hterm: ua[m][n] = betas (w*32+m*16+g*4..+4) at b=bh*32+n*16+r
    const ush* hbase = hws + (size_t)(bh * 32 + r) * NBETA + w * 32 + g * 4;
    u64 ua[2][2];
    #pragma unroll
    for (int m = 0; m < 2; ++m)
        #pragma unroll
        for (int n = 0; n < 2; ++n)
            ua[m][n] = *(const u64*)(hbase + n * (16 * NBETA) + m * 16);

    const int p0 = chunk * PPB;
    const float* vbase = V + (size_t)p0 * (CD * NB) + bh * 32 + bl;
    const int wswz = (bl & 15) << 4;   // staging/wsum swizzle
    const int rswz = r << 4;           // K-loop read swizzle

    float cacc[8];
    #pragma unroll
    for (int j = 0; j < 8; ++j) cacc[j] = 0.f;
    float lacc = 0.f;

    // prologue: stage pos0 -> buf0; issue pos1 loads into nv
    float nv[8];
    {
        #pragma unroll
        for (int j = 0; j < 8; ++j)
            nv[j] = __builtin_nontemporal_load(vbase + (cs * 8 + j) * NB);
        u32x4 pk = {cvtpk(nv[0], nv[1]), cvtpk(nv[2], nv[3]),
                    cvtpk(nv[4], nv[5]), cvtpk(nv[6], nv[7])};
        *(u32x4*)(VtB[0] + bl * 512 + ((cs * 16) ^ wswz)) = pk;
    }
    {
        const float* vp = vbase + (size_t)(CD * NB);
        #pragma unroll
        for (int j = 0; j < 8; ++j)
            nv[j] = __builtin_nontemporal_load(vp + (cs * 8 + j) * NB);
    }
    __syncthreads();

    int cur = 0, nxt = 16384;
    for (int i = 0; i < PPB; ++i) {
        const char* vt = VtB[0] + cur;

        // (1) stage pos i+1 (loads issued LAST iteration -> latency hidden)
        if (i + 1 < PPB) {
            u32x4 pk = {cvtpk(nv[0], nv[1]), cvtpk(nv[2], nv[3]),
                        cvtpk(nv[4], nv[5]), cvtpk(nv[6], nv[7])};
            *(u32x4*)(VtB[0] + nxt + bl * 512 + ((cs * 16) ^ wswz)) = pk;
        }
        // (2) issue pos i+2 loads (ds_write above read nv at issue -> WAR ok)
        if (i + 2 < PPB) {
            const float* vp = vbase + (size_t)(i + 2) * (CD * NB);
            #pragma unroll
            for (int j = 0; j < 8; ++j)
                nv[j] = __builtin_nontemporal_load(vp + (cs * 8 + j) * NB);
        }

        // (3) acc init = hterm; K-loop (A in regs, pure LDS+MFMA)
        f32x4 acc[2][2];
        #pragma unroll
        for (int m = 0; m < 2; ++m)
            #pragma unroll
            for (int n = 0; n < 2; ++n) {
                u64 h = ua[m][n];
                acc[m][n] = (f32x4){bf2f((ush)h), bf2f((ush)(h >> 16)),
                                    bf2f((ush)(h >> 32)), bf2f((ush)(h >> 48))};
            }
        const char* vrow = vt + r * 512;
        __builtin_amdgcn_s_setprio(1);
        #pragma unroll
        for (int ks = 0; ks < 8; ++ks) {
            const int off = ((ks << 6) | (g << 4)) ^ rswz;
            s16x8 b0 = *(const s16x8*)(vrow + off);
            s16x8 b1 = *(const s16x8*)(vrow + 8192 + off);
            #pragma unroll
            for (int m = 0; m < 2; ++m) {
                acc[m][0] = __builtin_amdgcn_mfma_f32_16x16x32_bf16(a[m][ks], b0, acc[m][0], 0, 0, 0);
                acc[m][1] = __builtin_amdgcn_mfma_f32_16x16x32_bf16(a[m][ks], b1, acc[m][1], 0, 0, 0);
            }
        }
        __builtin_amdgcn_s_setprio(0);

        // (4) epilogue: pe = base + sum nb*sigmoid; sigmoid = rcp(1+e^{2x})
        float pe0 = base, pe1 = base;
        #pragma unroll
        for (int m = 0; m < 2; ++m) {
            f32x4 nbv = *(const f32x4*)(&nbS[w * 32 + m * 16 + g * 4]);
            #pragma unroll
            for (int q = 0; q < 4; ++q) {
                float x0 = acc[m][0][q], x1 = acc[m][1][q];
                float s0 = __builtin_amdgcn_rcpf(1.f + fexp2(x0 * 2.8853900817779268f));
                float s1 = __builtin_amdgcn_rcpf(1.f + fexp2(x1 * 2.8853900817779268f));
                pe0 = fmaf(nbv[q], s0, pe0);
                pe1 = fmaf(nbv[q], s1, pe1);
            }
        }
        pe0 += __shfl_xor(pe0, 16, 64); pe0 += __shfl_xor(pe0, 32, 64);
        pe1 += __shfl_xor(pe1, 16, 64); pe1 += __shfl_xor(pe1, 32, 64);
        if (l < 16) { ew[i & 1][w][l] = pe0; ew[i & 1][w][16 + l] = pe1; }

        __syncthreads();   // the ONLY barrier per position

        // (5) wsum from the staged tile (no 2nd HBM pass)
        float e = bbias;
        #pragma unroll
        for (int wv = 0; wv < 16; ++wv) e += ew[i & 1][wv][bl];
        float wgt = __expf(e);
        lacc += wgt;
        s16x8 v = *(const s16x8*)(vt + bl * 512 + ((cs * 16) ^ wswz));
        #pragma unroll
        for (int j = 0; j < 8; ++j)
            cacc[j] = fmaf(wgt, bf2f((ush)v[j]), cacc[j]);

        cur = nxt;
        nxt += 16384;
        if (nxt == 49152) nxt = 0;
    }

    // partials: num[block][32 b][256 c]
    float* np = num + (size_t)blockIdx.x * (32 * CD) + bl * CD + cs * 8;
    *(f32x4*)(np)     = (f32x4){cacc[0], cacc[1], cacc[2], cacc[3]};
    *(f32x4*)(np + 4) = (f32x4){cacc[4], cacc[5], cacc[6], cacc[7]};
    if (cs == 0) lsum[blockIdx.x * 32 + bl] = lacc;
}

// ---------------------------------------------------------------------------
// Combine: out[b][c] = sum_ch num[ch*2+bh][bl][c] / sum_ch lsum[ch*2+bh][bl]
// ---------------------------------------------------------------------------
__global__ __launch_bounds__(256) void combine3(
    const float* __restrict__ num, const float* __restrict__ lsum,
    float* __restrict__ out)
{
    const int b = blockIdx.x, c = threadIdx.x;
    const int bh = b >> 5, bl = b & 31;
    float s0 = 0.f, s1 = 0.f, ls = 0.f;
    #pragma unroll 4
    for (int ch = 0; ch < 128; ch += 2) {
        const int w0 = ch * 2 + bh, w1 = (ch + 1) * 2 + bh;
        s0 += num[(size_t)w0 * (32 * CD) + bl * CD + c];
        s1 += num[(size_t)w1 * (32 * CD) + bl * CD + c];
        ls += lsum[w0 * 32 + bl] + lsum[w1 * 32 + bl];
    }
    out[b * CD + c] = (s0 + s1) / ls;
}

extern "C" void kernel_launch(void* const* d_in, const int* in_sizes, int n_in,
                              void* d_out, int out_size, void* d_ws, size_t ws_size,
                              hipStream_t stream)
{
    (void)in_sizes; (void)n_in; (void)out_size; (void)ws_size;
    const float* V      = (const float*)d_in[0];
    const float* h_t    = (const float*)d_in[1];
    const float* W_h_w  = (const float*)d_in[2];
    const float* W_h_b  = (const float*)d_in[3];
    const float* W_w    = (const float*)d_in[4];
    const float* W_b    = (const float*)d_in[5];
    const float* beta_w = (const float*)d_in[6];
    const float* beta_b = (const float*)d_in[7];

    char* ws = (char*)d_ws;
    ush*   wwb = (ush*)ws;                                   // 256 KB
    ush*   hws = (ush*)(ws + 262144);                        // 64 KB
    float* num = (float*)(ws + 262144 + 65536);              // 8.4 MB
    float* lsm = (float*)(ws + 262144 + 65536 + 8388608);    // 32 KB

    hipLaunchKernelGGL(prep_kernel, dim3(96), dim3(512), 0, stream,
                       h_t, W_h_w, W_h_b, W_w, W_b, hws, wwb);
    hipLaunchKernelGGL(fused, dim3(256), dim3(1024), 0, stream,
                       V, wwb, hws, beta_w, beta_b, num, lsm);
    hipLaunchKernelGGL(combine3, dim3(64), dim3(256), 0, stream,
                       num, lsm, (float*)d_out);
}

// Round 9
// 151.583 us; speedup vs baseline: 1.3975x; 1.2280x over previous
//
#include <hip/hip_runtime.h>

typedef float f32x4 __attribute__((ext_vector_type(4)));
typedef short s16x8 __attribute__((ext_vector_type(8)));
typedef unsigned int u32;
typedef u32 u32x4 __attribute__((ext_vector_type(4)));
typedef unsigned long long u64;
typedef unsigned short ush;

#define CD    256
#define NB    64
#define NBETA 512
#define NHID  512
#define PPB   32    // positions per fused block

__device__ __forceinline__ ush f2bf(float x) {
    u32 u = __builtin_bit_cast(u32, x);
    u += 0x7fffu + ((u >> 16) & 1u);
    return (ush)(u >> 16);
}
__device__ __forceinline__ float bf2f(ush h) {
    u32 u = ((u32)h) << 16;
    return __builtin_bit_cast(float, u);
}
__device__ __forceinline__ u32 cvtpk(float lo, float hi) {
    u32 r;
    asm("v_cvt_pk_bf16_f32 %0, %1, %2" : "=v"(r) : "v"(lo), "v"(hi));
    return r;
}
__device__ __forceinline__ float fexp2(float x) {  // 2^x
    float r;
    asm("v_exp_f32 %0, %1" : "=v"(r) : "v"(x));
    return r;
}

// ---------------------------------------------------------------------------
// Prep: hws[b][beta] = h_t[b]·W_h_w[beta] + W_h_b[beta] + W_b[beta] (bf16);
//       wwb = bf16(W_w) [512][256].   (unchanged, round-8 proven)
// ---------------------------------------------------------------------------
__global__ __launch_bounds__(512) void prep_kernel(
    const float* __restrict__ h_t, const float* __restrict__ W_h_w,
    const float* __restrict__ W_h_b, const float* __restrict__ W_w,
    const float* __restrict__ W_b,
    ush* __restrict__ hws, ush* __restrict__ wwb)
{
    const int blk = blockIdx.x;
    const int tid = threadIdx.x;
    if (blk < NB) {
        __shared__ float hrow[NHID];
        hrow[tid] = h_t[blk * NHID + tid];
        __syncthreads();
        const float* wr = W_h_w + tid * NHID;
        float a0 = 0.f, a1 = 0.f, a2 = 0.f, a3 = 0.f;
        #pragma unroll 4
        for (int h = 0; h < NHID; h += 4) {
            f32x4 wv = *(const f32x4*)(wr + h);
            a0 = fmaf(wv.x, hrow[h], a0);
            a1 = fmaf(wv.y, hrow[h + 1], a1);
            a2 = fmaf(wv.z, hrow[h + 2], a2);
            a3 = fmaf(wv.w, hrow[h + 3], a3);
        }
        float acc = (a0 + a1) + (a2 + a3) + W_h_b[tid] + W_b[tid];
        hws[blk * NBETA + tid] = f2bf(acc);   // [b][beta]
    } else {
        const int idx = ((blk - NB) * 512 + tid) * 8;
        f32x4 a = *(const f32x4*)(W_w + idx);
        f32x4 b = *(const f32x4*)(W_w + idx + 4);
        s16x8 pk;
        pk[0] = (short)f2bf(a.x); pk[1] = (short)f2bf(a.y);
        pk[2] = (short)f2bf(a.z); pk[3] = (short)f2bf(a.w);
        pk[4] = (short)f2bf(b.x); pk[5] = (short)f2bf(b.y);
        pk[6] = (short)f2bf(b.z); pk[7] = (short)f2bf(b.w);
        *(s16x8*)(wwb + idx) = pk;
    }
}

// ---------------------------------------------------------------------------
// Fused: 512 thr = 8 waves x 64 betas (all 512), block = (b-half, 32 pos).
// V read from HBM once. vs round 8: waves halved -> K-loop LDS traffic
// halves (8x16KB/iter); A = a[4][8] = 128 VGPR at (512,2) 256-reg budget;
// intra-position pipelining (Kchain-n0 / epi-n0 / Kchain-n1 / epi-n1);
// ew in [b][wave] pad-12 layout read as 2x b128. Staging/swizzle/3-buffer/
// 1-barrier schedule identical to round 8 (proven).
// ---------------------------------------------------------------------------
__global__ __launch_bounds__(512, 2) void fused(
    const float* __restrict__ V,
    const ush* __restrict__ wwb,
    const ush* __restrict__ hws,
    const float* __restrict__ beta_w,
    const float* __restrict__ beta_b,
    float* __restrict__ num,
    float* __restrict__ lsum)
{
    __shared__ __align__(16) char VtB[3][16384];   // [32 b][256 c] bf16 swz
    __shared__ float nbS[NBETA];                   // -2*beta_w
    __shared__ __align__(16) float ew2[2][32][12]; // [parity][b][wave], pad 12

    const int tid = threadIdx.x;
    const int l = tid & 63, w = tid >> 6, g = l >> 4, r = l & 15;
    const int bl = tid & 31, cs = tid >> 5;        // b-lane, c-slice of 16
    const int bh = blockIdx.x & 1, chunk = blockIdx.x >> 1;

    nbS[tid] = -2.f * beta_w[tid];
    const float bbias = beta_b[0];

    // base = sum of this lane's 16 bw values (position-invariant)
    float base = 0.f;
    #pragma unroll
    for (int m = 0; m < 4; ++m) {
        f32x4 t = *(const f32x4*)(beta_w + w * 64 + m * 16 + g * 4);
        base += (t.x + t.y) + (t.z + t.w);
    }

    // permanent A fragments: beta = w*64 + m*16 + r  (128 VGPR)
    const ush* wbase = wwb + (size_t)(w * 64 + r) * CD + g * 8;
    s16x8 a[4][8];
    #pragma unroll
    for (int m = 0; m < 4; ++m)
        #pragma unroll
        for (int ks = 0; ks < 8; ++ks)
            a[m][ks] = *(const s16x8*)(wbase + m * (16 * CD) + ks * 32);

    // permanent hterm: ua[m][n] = betas (w*64+m*16+g*4..+3) at b=bh*32+n*16+r
    const ush* hbase = hws + (size_t)(bh * 32 + r) * NBETA + w * 64 + g * 4;
    u64 ua[4][2];
    #pragma unroll
    for (int m = 0; m < 4; ++m)
        #pragma unroll
        for (int n = 0; n < 2; ++n)
            ua[m][n] = *(const u64*)(hbase + n * (16 * NBETA) + m * 16);

    const int p0 = chunk * PPB;
    const float* vbase = V + (size_t)p0 * (CD * NB) + bh * 32 + bl;
    const int wswz = (bl & 15) << 4;   // staging/wsum swizzle (row fn)
    const int rswz = r << 4;           // K-loop read swizzle (same row fn)

    float cacc[16];
    #pragma unroll
    for (int j = 0; j < 16; ++j) cacc[j] = 0.f;
    float lacc = 0.f;

    // prologue: stage pos0 -> buf0; issue pos1 loads into nv
    float nv[16];
    {
        #pragma unroll
        for (int j = 0; j < 16; ++j)
            nv[j] = __builtin_nontemporal_load(vbase + (cs * 16 + j) * NB);
        char* db = VtB[0] + bl * 512;
        u32x4 pk0 = {cvtpk(nv[0], nv[1]), cvtpk(nv[2], nv[3]),
                     cvtpk(nv[4], nv[5]), cvtpk(nv[6], nv[7])};
        *(u32x4*)(db + ((cs * 32) ^ wswz)) = pk0;
        u32x4 pk1 = {cvtpk(nv[8], nv[9]), cvtpk(nv[10], nv[11]),
                     cvtpk(nv[12], nv[13]), cvtpk(nv[14], nv[15])};
        *(u32x4*)(db + ((cs * 32 + 16) ^ wswz)) = pk1;
    }
    {
        const float* vp = vbase + (size_t)(CD * NB);
        #pragma unroll
        for (int j = 0; j < 16; ++j)
            nv[j] = __builtin_nontemporal_load(vp + (cs * 16 + j) * NB);
    }
    __syncthreads();

    int cur = 0, nxt = 16384;
    for (int i = 0; i < PPB; ++i) {
        const char* vt = VtB[0] + cur;

        // (1) stage pos i+1 (loads issued LAST iteration)
        if (i + 1 < PPB) {
            char* db = VtB[0] + nxt + bl * 512;
            u32x4 pk0 = {cvtpk(nv[0], nv[1]), cvtpk(nv[2], nv[3]),
                         cvtpk(nv[4], nv[5]), cvtpk(nv[6], nv[7])};
            *(u32x4*)(db + ((cs * 32) ^ wswz)) = pk0;
            u32x4 pk1 = {cvtpk(nv[8], nv[9]), cvtpk(nv[10], nv[11]),
                         cvtpk(nv[12], nv[13]), cvtpk(nv[14], nv[15])};
            *(u32x4*)(db + ((cs * 32 + 16) ^ wswz)) = pk1;
        }
        // (2) issue pos i+2 loads
        if (i + 2 < PPB) {
            const float* vp = vbase + (size_t)(i + 2) * (CD * NB);
            #pragma unroll
            for (int j = 0; j < 16; ++j)
                nv[j] = __builtin_nontemporal_load(vp + (cs * 16 + j) * NB);
        }

        const char* vrow = vt + r * 512;

        // (3) n=0: init from ua, K-chain, epilogue (overlaps n=1 K-chain)
        f32x4 acc0[4];
        #pragma unroll
        for (int m = 0; m < 4; ++m) {
            u64 h = ua[m][0];
            acc0[m] = (f32x4){bf2f((ush)h), bf2f((ush)(h >> 16)),
                              bf2f((ush)(h >> 32)), bf2f((ush)(h >> 48))};
        }
        #pragma unroll
        for (int ks = 0; ks < 8; ++ks) {
            const int off = ((ks << 6) | (g << 4)) ^ rswz;
            s16x8 b0 = *(const s16x8*)(vrow + off);
            #pragma unroll
            for (int m = 0; m < 4; ++m)
                acc0[m] = __builtin_amdgcn_mfma_f32_16x16x32_bf16(a[m][ks], b0, acc0[m], 0, 0, 0);
        }
        float pe0 = base;
        #pragma unroll
        for (int m = 0; m < 4; ++m) {
            f32x4 nbv = *(const f32x4*)(&nbS[w * 64 + m * 16 + g * 4]);
            #pragma unroll
            for (int q = 0; q < 4; ++q) {
                float s = __builtin_amdgcn_rcpf(
                    1.f + fexp2(acc0[m][q] * 2.8853900817779268f));
                pe0 = fmaf(nbv[q], s, pe0);
            }
        }

        // (4) n=1: init, K-chain, epilogue
        f32x4 acc1[4];
        #pragma unroll
        for (int m = 0; m < 4; ++m) {
            u64 h = ua[m][1];
            acc1[m] = (f32x4){bf2f((ush)h), bf2f((ush)(h >> 16)),
                              bf2f((ush)(h >> 32)), bf2f((ush)(h >> 48))};
        }
        #pragma unroll
        for (int ks = 0; ks < 8; ++ks) {
            const int off = ((ks << 6) | (g << 4)) ^ rswz;
            s16x8 b1 = *(const s16x8*)(vrow + 8192 + off);
            #pragma unroll
            for (int m = 0; m < 4; ++m)
                acc1[m] = __builtin_amdgcn_mfma_f32_16x16x32_bf16(a[m][ks], b1, acc1[m], 0, 0, 0);
        }
        float pe1 = base;
        #pragma unroll
        for (int m = 0; m < 4; ++m) {
            f32x4 nbv = *(const f32x4*)(&nbS[w * 64 + m * 16 + g * 4]);
            #pragma unroll
            for (int q = 0; q < 4; ++q) {
                float s = __builtin_amdgcn_rcpf(
                    1.f + fexp2(acc1[m][q] * 2.8853900817779268f));
                pe1 = fmaf(nbv[q], s, pe1);
            }
        }

        // (5) cross-lane reduce (over g) + partial store
        pe0 += __shfl_xor(pe0, 16, 64); pe0 += __shfl_xor(pe0, 32, 64);
        pe1 += __shfl_xor(pe1, 16, 64); pe1 += __shfl_xor(pe1, 32, 64);
        if (l < 16) { ew2[i & 1][l][w] = pe0; ew2[i & 1][16 + l][w] = pe1; }

        __syncthreads();   // the ONLY barrier per position

        // (6) e-sum (2x b128) + wsum from the staged tile
        const float* er = &ew2[i & 1][bl][0];
        f32x4 s4 = *(const f32x4*)er + *(const f32x4*)(er + 4);
        float e = bbias + (s4.x + s4.y) + (s4.z + s4.w);
        float wgt = __expf(e);
        lacc += wgt;
        const char* vb = vt + bl * 512;
        #pragma unroll
        for (int k = 0; k < 2; ++k) {
            s16x8 v = *(const s16x8*)(vb + ((cs * 32 + k * 16) ^ wswz));
            #pragma unroll
            for (int j = 0; j < 8; ++j)
                cacc[k * 8 + j] = fmaf(wgt, bf2f((ush)v[j]), cacc[k * 8 + j]);
        }

        cur = nxt;
        nxt += 16384;
        if (nxt == 49152) nxt = 0;
    }

    // partials: num[block][32 b][256 c]
    float* np = num + (size_t)blockIdx.x * (32 * CD) + bl * CD + cs * 16;
    #pragma unroll
    for (int k = 0; k < 4; ++k)
        *(f32x4*)(np + k * 4) =
            (f32x4){cacc[k * 4], cacc[k * 4 + 1], cacc[k * 4 + 2], cacc[k * 4 + 3]};
    if (cs == 0) lsum[blockIdx.x * 32 + bl] = lacc;
}

// ---------------------------------------------------------------------------
// Combine: 256 blocks = (b 64 x cq 4); 256 thr = (cl 64 x kq 4).
// out[b][c] = sum_ch num[ch*2+bh][bl][c] / sum_ch lsum[ch*2+bh][bl]
// ---------------------------------------------------------------------------
__global__ __launch_bounds__(256) void combine4(
    const float* __restrict__ num, const float* __restrict__ lsum,
    float* __restrict__ out)
{
    __shared__ float rs[4][64];
    __shared__ float rl[4][64];
    const int b = blockIdx.x >> 2, cq = blockIdx.x & 3;
    const int bh = b >> 5, blr = b & 31;
    const int cl = threadIdx.x & 63, kq = threadIdx.x >> 6;

    float s = 0.f, ls = 0.f;
    #pragma unroll 4
    for (int ch = kq * 32; ch < kq * 32 + 32; ++ch) {
        const int blk = ch * 2 + bh;
        s += num[(size_t)blk * (32 * CD) + blr * CD + cq * 64 + cl];
        ls += lsum[blk * 32 + blr];
    }
    rs[kq][cl] = s; rl[kq][cl] = ls;
    __syncthreads();
    if (kq == 0) {
        float sn = rs[0][cl] + rs[1][cl] + rs[2][cl] + rs[3][cl];
        float sl = rl[0][cl] + rl[1][cl] + rl[2][cl] + rl[3][cl];
        out[b * CD + cq * 64 + cl] = sn / sl;
    }
}

extern "C" void kernel_launch(void* const* d_in, const int* in_sizes, int n_in,
                              void* d_out, int out_size, void* d_ws, size_t ws_size,
                              hipStream_t stream)
{
    (void)in_sizes; (void)n_in; (void)out_size; (void)ws_size;
    const float* V      = (const float*)d_in[0];
    const float* h_t    = (const float*)d_in[1];
    const float* W_h_w  = (const float*)d_in[2];
    const float* W_h_b  = (const float*)d_in[3];
    const float* W_w    = (const float*)d_in[4];
    const float* W_b    = (const float*)d_in[5];
    const float* beta_w = (const float*)d_in[6];
    const float* beta_b = (const float*)d_in[7];

    char* ws = (char*)d_ws;
    ush*   wwb = (ush*)ws;                                   // 256 KB
    ush*   hws = (ush*)(ws + 262144);                        // 64 KB
    float* num = (float*)(ws + 262144 + 65536);              // 8.4 MB
    float* lsm = (float*)(ws + 262144 + 65536 + 8388608);    // 32 KB

    hipLaunchKernelGGL(prep_kernel, dim3(96), dim3(512), 0, stream,
                       h_t, W_h_w, W_h_b, W_w, W_b, hws, wwb);
    hipLaunchKernelGGL(fused, dim3(256), dim3(512), 0, stream,
                       V, wwb, hws, beta_w, beta_b, num, lsm);
    hipLaunchKernelGGL(combine4, dim3(256), dim3(256), 0, stream,
                       num, lsm, (float*)d_out);
}